// Round 5
// baseline (2404.512 us; speedup 1.0000x reference)
//
#include <hip/hip_runtime.h>
#include <hip/hip_bf16.h>

// GatedLSTM: B=64, T=256, IN=512, H=1024. i-gate dead in reference -> dropped.
// Recurrent exchange: unique-address rotation hx[t] (chunk layout) with
// NaN-SENTINEL dataflow: hx[t>0] pre-filled with 0xFFFF (bf16 -NaN, impossible
// as a real h = sigmoid*c value). Producer publishes h by simply storing it
// (agent-scope dword, atomic per dword). Consumer loads A-fragments with
// agent-scope 8B atomic loads (L2-bypass) and retries until no dword is
// 0xFFFFFFFF -> poll and data fetch are the SAME MALL round trip. No drains,
// no sentinels, no barriers, per-dword publish granularity.

typedef __attribute__((ext_vector_type(8))) short bfrag;   // 8 x bf16 (4 VGPR)
typedef __attribute__((ext_vector_type(4))) float f32x4;   // MFMA accumulator

__device__ __forceinline__ unsigned short f2b(float v) {
  __hip_bfloat16 h = __float2bfloat16(v);
  union { __hip_bfloat16 h; unsigned short u; } c; c.h = h; return c.u;
}
__device__ __forceinline__ float b2f(unsigned short u) {
  union { unsigned int i; float f; } c; c.i = ((unsigned int)u) << 16; return c.f;
}
__device__ __forceinline__ float sigm(float x) { return 1.0f / (1.0f + __expf(-x)); }
__device__ __forceinline__ float tanh_f(float x) {
  float e = __expf(2.0f * x);
  return (e - 1.0f) / (e + 1.0f);
}

// ---------------------------------------------------------------------------
// Phase 1: x-projections (unchanged). mlx[t][g][j][b] bf16.
// ---------------------------------------------------------------------------
__global__ __launch_bounds__(512, 2) void xproj_kernel(
    const float* __restrict__ inp,
    const float* __restrict__ Wf, const float* __restrict__ Wmf,
    const float* __restrict__ Wo, const float* __restrict__ Wmo,
    const float* __restrict__ Wc, const float* __restrict__ Wmc,
    unsigned short* __restrict__ mlx)
{
  __shared__ unsigned short Al[256 * 128];  // 64 KB, XOR-swizzled rows
  __shared__ unsigned short Bl[256 * 128];  // 64 KB

  const int tid = threadIdx.x;
  const int w = tid >> 6, l = tid & 63;
  const int c = l & 15, g4 = l >> 4;
  const int jc = blockIdx.x, gate = blockIdx.y, tq = blockIdx.z;
  const float* W  = (gate == 0) ? Wf  : (gate == 1) ? Wo  : Wc;
  const float* Wm = (gate == 0) ? Wmf : (gate == 1) ? Wmo : Wmc;
  const int j0 = jc * 128;

  f32x4 acc[2][16];
#pragma unroll
  for (int mi = 0; mi < 2; ++mi)
#pragma unroll
    for (int ni = 0; ni < 16; ++ni) acc[mi][ni] = (f32x4){0.f, 0.f, 0.f, 0.f};

  for (int kc = 0; kc < 4; ++kc) {
#pragma unroll
    for (int i = 0; i < 16; ++i) {
      int idx = tid + i * 512;      // 0..8191
      int row = idx >> 5;           // 0..255
      int xl  = idx & 31;           // 16B unit within 128-float chunk
      int b_ = row & 63, tl = row >> 6;
      const float4 va = *(const float4*)(inp + (size_t)(b_ * 256 + tq * 4 + tl) * 512 + kc * 128 + xl * 4);
      ushort4 pa;
      pa.x = f2b(va.x); pa.y = f2b(va.y); pa.z = f2b(va.z); pa.w = f2b(va.w);
      *(ushort4*)((char*)Al + ((row * 256 + xl * 8) ^ ((row & 7) << 4))) = pa;
      const float* src = (row < 128) ? (W + (size_t)(j0 + row) * 512)
                                     : (Wm + (size_t)(j0 + row - 128) * 512);
      const float4 vb = *(const float4*)(src + kc * 128 + xl * 4);
      ushort4 pb;
      pb.x = f2b(vb.x); pb.y = f2b(vb.y); pb.z = f2b(vb.z); pb.w = f2b(vb.w);
      *(ushort4*)((char*)Bl + ((row * 256 + xl * 8) ^ ((row & 7) << 4))) = pb;
    }
    __syncthreads();
#pragma unroll
    for (int ks = 0; ks < 4; ++ks) {
      const int koff = (ks * 32 + g4 * 8) * 2;
      bfrag af[2];
#pragma unroll
      for (int mi = 0; mi < 2; ++mi) {
        int row = w * 32 + mi * 16 + c;
        af[mi] = *(const bfrag*)((const char*)Al + ((row * 256 + koff) ^ ((row & 7) << 4)));
      }
#pragma unroll
      for (int ni = 0; ni < 16; ++ni) {
        int n = ni * 16 + c;
        bfrag bf = *(const bfrag*)((const char*)Bl + ((n * 256 + koff) ^ ((n & 7) << 4)));
#pragma unroll
        for (int mi = 0; mi < 2; ++mi)
          acc[mi][ni] = __builtin_amdgcn_mfma_f32_16x16x32_bf16(af[mi], bf, acc[mi][ni], 0, 0, 0);
      }
    }
    __syncthreads();
  }
#pragma unroll
  for (int mi = 0; mi < 2; ++mi) {
#pragma unroll
    for (int ni = 0; ni < 8; ++ni) {
      f32x4 xw = acc[mi][ni];
      f32x4 xm = acc[mi][ni + 8];
      ushort4 st;
      st.x = f2b(xw[0] * sigm(xm[0]));
      st.y = f2b(xw[1] * sigm(xm[1]));
      st.z = f2b(xw[2] * sigm(xm[2]));
      st.w = f2b(xw[3] * sigm(xm[3]));
      int row = w * 32 + mi * 16 + g4 * 4;
      int tl = row >> 6, b_ = row & 63;
      int j = j0 + ni * 16 + c;
      size_t addr = ((size_t)((tq * 4 + tl) * 3 + gate) * 1024 + j) * 64 + b_;
      *(ushort4*)(mlx + addr) = st;
    }
  }
}

// ---------------------------------------------------------------------------
// Phase 2: persistent recurrent kernel, NaN-sentinel dataflow. 128 blocks x
// 256 threads, 1 block/CU (104 KB LDS). Block owns h-cols j0=8*bid..+8.
// hx chunk layout: hx[t][kb][b][8] bf16 (kb = chunk = block id).
// Per step per wave: ks-batched {retry-load 4 A-frags via 8B agent atomic
// loads until no dword == 0xFFFFFFFF -> MFMA} (poll==fetch, pipelined over
// producers) -> ds_write partials (double-buffered) -> one barrier -> gates
// -> packed h dword agent-store (the publish; nothing after it).
// ---------------------------------------------------------------------------
__global__ __launch_bounds__(256, 1) void recur_kernel(
    const float* __restrict__ Uf, const float* __restrict__ Umf,
    const float* __restrict__ Uo, const float* __restrict__ Umo,
    const float* __restrict__ Uc, const float* __restrict__ Umc,
    const float* __restrict__ bfp, const float* __restrict__ bop,
    const float* __restrict__ bcp,
    const unsigned short* __restrict__ mlx,  // [256][3][1024][64] bf16
    unsigned short* __restrict__ hx,         // [257][128][64][8] bf16
    float* __restrict__ cfin)                // [1024][64] f32
{
  __shared__ float prep[2][4 * 48 * 68];     // 2 x 52 KB partials [w][col][row]

  // One-time L1+L2 invalidate: discards poison-epoch / cross-replay lines.
  __builtin_amdgcn_fence(__ATOMIC_ACQUIRE, "agent");

  const int tid = threadIdx.x;
  const int bid = blockIdx.x;
  const int w = tid >> 6, l = tid & 63;
  const int c = l & 15, g4 = l >> 4;
  const int j0 = bid * 8;

  // ---- one-time U stage into registers: Breg[nt][ks] -------------------
  bfrag Breg[3][8];
#pragma unroll
  for (int nt = 0; nt < 3; ++nt) {
    const int n = nt * 16 + c;          // 0..47
    const int mi6 = n >> 3;             // 0..5 (ternary chain: no scratch)
    const float* src = (mi6 == 0) ? Uf : (mi6 == 1) ? Umf : (mi6 == 2) ? Uo
                     : (mi6 == 3) ? Umo : (mi6 == 4) ? Uc : Umc;
    src += (size_t)(j0 + (n & 7)) * 1024;
#pragma unroll
    for (int ks = 0; ks < 8; ++ks) {
      const int k = w * 256 + ks * 32 + g4 * 8;
      const float4 v0 = *(const float4*)(src + k);
      const float4 v1 = *(const float4*)(src + k + 4);
      bfrag b;
      b[0] = (short)f2b(v0.x); b[1] = (short)f2b(v0.y);
      b[2] = (short)f2b(v0.z); b[3] = (short)f2b(v0.w);
      b[4] = (short)f2b(v1.x); b[5] = (short)f2b(v1.y);
      b[6] = (short)f2b(v1.z); b[7] = (short)f2b(v1.w);
      Breg[nt][ks] = b;
    }
  }

  const int bb = l;               // elementwise: b = lane, cols cl0 = 2w
  const int cl0 = w * 2;
  float bias[2][3], cr[2] = {0.f, 0.f};
#pragma unroll
  for (int q = 0; q < 2; ++q) {
    bias[q][0] = bfp[j0 + cl0 + q];
    bias[q][1] = bop[j0 + cl0 + q];
    bias[q][2] = bcp[j0 + cl0 + q];
  }

  for (int t = 0; t < 256; ++t) {
    // mlx for THIS step's gates: issue now, latency hides under producer wait
    float mfv[2], mov[2], mcv[2];
    {
      size_t mb = (size_t)t * 3 * 65536 + (size_t)(j0 + cl0) * 64 + bb;
#pragma unroll
      for (int q = 0; q < 2; ++q) {
        mfv[q] = b2f(mlx[mb + q * 64]);
        mov[q] = b2f(mlx[mb + 65536 + q * 64]);
        mcv[q] = b2f(mlx[mb + 2 * 65536 + q * 64]);
      }
    }

    f32x4 acc[4][3];
#pragma unroll
    for (int mi = 0; mi < 4; ++mi)
#pragma unroll
      for (int nt = 0; nt < 3; ++nt) acc[mi][nt] = (f32x4){0.f, 0.f, 0.f, 0.f};

#pragma unroll
    for (int ks = 0; ks < 8; ++ks) {
      const int kb = w * 32 + ks * 4 + g4;   // wave-private chunk ids
      // row (mi*16+c) of chunk kb; row stride = 16B = 2 ull
      const unsigned long long* rowp =
          (const unsigned long long*)(hx + (((size_t)t * 128 + kb) * 64 + c) * 8);
      unsigned long long q0[4], q1[4];
      while (true) {
        bool ok = true;
#pragma unroll
        for (int mi = 0; mi < 4; ++mi) {
          q0[mi] = __hip_atomic_load(rowp + mi * 32,     __ATOMIC_RELAXED, __HIP_MEMORY_SCOPE_AGENT);
          q1[mi] = __hip_atomic_load(rowp + mi * 32 + 1, __ATOMIC_RELAXED, __HIP_MEMORY_SCOPE_AGENT);
        }
#pragma unroll
        for (int mi = 0; mi < 4; ++mi) {
          ok = ok && ((unsigned)(q0[mi])       != 0xFFFFFFFFu)
                  && ((unsigned)(q0[mi] >> 32) != 0xFFFFFFFFu)
                  && ((unsigned)(q1[mi])       != 0xFFFFFFFFu)
                  && ((unsigned)(q1[mi] >> 32) != 0xFFFFFFFFu);
        }
        if (__all(ok)) break;
      }
#pragma unroll
      for (int mi = 0; mi < 4; ++mi) {
        union { unsigned long long q[2]; bfrag f; } u;
        u.q[0] = q0[mi]; u.q[1] = q1[mi];
#pragma unroll
        for (int nt = 0; nt < 3; ++nt)
          acc[mi][nt] = __builtin_amdgcn_mfma_f32_16x16x32_bf16(u.f, Breg[nt][ks], acc[mi][nt], 0, 0, 0);
      }
    }

    float* pp = prep[t & 1];
#pragma unroll
    for (int mi = 0; mi < 4; ++mi)
#pragma unroll
      for (int nt = 0; nt < 3; ++nt) {
        int col = nt * 16 + c;
        *(f32x4*)&pp[(w * 48 + col) * 68 + mi * 16 + g4 * 4] = acc[mi][nt];
      }
    __syncthreads();   // the ONLY per-step barrier (prep double-buffered)

    unsigned int pack = 0;
#pragma unroll
    for (int q = 0; q < 2; ++q) {
      const int cl = cl0 + q;
      float s[6];
#pragma unroll
      for (int m = 0; m < 6; ++m) {
        const int col = m * 8 + cl;
        s[m] = pp[col * 68 + bb] + pp[(48 + col) * 68 + bb] +
               pp[(96 + col) * 68 + bb] + pp[(144 + col) * 68 + bb];
      }
      float fg = sigm(mfv[q] + sigm(s[1]) * s[0] + bias[q][0]);
      float og = sigm(mov[q] + sigm(s[3]) * s[2] + bias[q][1]);
      float cd = tanh_f(mcv[q] + sigm(s[5]) * s[4] + bias[q][2]);
      cr[q] = fg * cr[q] + cd;
      float hv = og * cr[q];
      pack |= (unsigned int)f2b(hv) << (16 * q);
      if (t == 255) cfin[(size_t)(j0 + cl) * 64 + bb] = cr[q];
    }
    // publish: packed h dword (never == 0xFFFFFFFF since h is never NaN)
    __hip_atomic_store(
        (unsigned int*)(hx + ((((size_t)(t + 1) * 128 + bid) * 64 + bb) * 8 + cl0)),
        pack, __ATOMIC_RELAXED, __HIP_MEMORY_SCOPE_AGENT);
  }
}

// ---------------------------------------------------------------------------
// Phase 3: hx chunks -> out [b][t][j] f32 (streaming cast)
// ---------------------------------------------------------------------------
__global__ __launch_bounds__(128) void histcast_kernel(
    const unsigned short* __restrict__ hx, float* __restrict__ out)
{
  const int b = blockIdx.x >> 8, t = blockIdx.x & 255;
  const int j = threadIdx.x * 8;
  const unsigned short* src = hx + (((size_t)(t + 1) * 128 + (j >> 3)) * 64 + b) * 8;
  float* dst = out + ((size_t)b * 256 + t) * 1024 + j;
  ushort4 v0 = *(const ushort4*)(src);
  ushort4 v1 = *(const ushort4*)(src + 4);
  float4 o0, o1;
  o0.x = b2f(v0.x); o0.y = b2f(v0.y); o0.z = b2f(v0.z); o0.w = b2f(v0.w);
  o1.x = b2f(v1.x); o1.y = b2f(v1.y); o1.z = b2f(v1.z); o1.w = b2f(v1.w);
  *(float4*)(dst) = o0;
  *(float4*)(dst + 4) = o1;
}

__global__ __launch_bounds__(256) void finals_kernel(
    const unsigned short* __restrict__ hx, const float* __restrict__ cfin,
    float* __restrict__ out)
{
  int tid = blockIdx.x * 256 + threadIdx.x;  // 0..65535 = b*1024 + j
  int b = tid >> 10, j = tid & 1023;
  out[16777216 + tid]         = b2f(hx[(((size_t)256 * 128 + (j >> 3)) * 64 + b) * 8 + (j & 7)]);
  out[16777216 + 65536 + tid] = cfin[(size_t)j * 64 + b];
}

// ---------------------------------------------------------------------------
extern "C" void kernel_launch(void* const* d_in, const int* in_sizes, int n_in,
                              void* d_out, int out_size, void* d_ws, size_t ws_size,
                              hipStream_t stream)
{
  const float* input = (const float*)d_in[0];
  const float* W_f  = (const float*)d_in[1];
  const float* Wm_f = (const float*)d_in[2];
  const float* U_f  = (const float*)d_in[3];
  const float* Um_f = (const float*)d_in[4];
  const float* b_f  = (const float*)d_in[5];
  const float* W_o  = (const float*)d_in[11];
  const float* Wm_o = (const float*)d_in[12];
  const float* U_o  = (const float*)d_in[13];
  const float* Um_o = (const float*)d_in[14];
  const float* b_o  = (const float*)d_in[15];
  const float* W_c  = (const float*)d_in[16];
  const float* Wm_c = (const float*)d_in[17];
  const float* U_c  = (const float*)d_in[18];
  const float* Um_c = (const float*)d_in[19];
  const float* b_c  = (const float*)d_in[20];

  char* ws = (char*)d_ws;
  size_t off = 0;
  unsigned short* mlx = (unsigned short*)(ws + off); off += (size_t)256 * 3 * 1024 * 64 * 2; // 100.7 MB
  unsigned short* hx  = (unsigned short*)(ws + off); off += (size_t)257 * 128 * 64 * 8 * 2;  //  33.7 MB
  float* cfin = (float*)(ws + off);                  off += (size_t)1024 * 64 * 4;
  if (off > ws_size) return;  // insufficient workspace: bail cleanly

  hipMemsetAsync(hx, 0, 131072, stream);                              // h0 = 0
  hipMemsetAsync((char*)hx + 131072, 0xFF, (size_t)256 * 131072, stream); // NaN sentinels

  xproj_kernel<<<dim3(8, 3, 64), 512, 0, stream>>>(input, W_f, Wm_f, W_o, Wm_o, W_c, Wm_c, mlx);
  recur_kernel<<<128, 256, 0, stream>>>(U_f, Um_f, U_o, Um_o, U_c, Um_c,
                                        b_f, b_o, b_c, mlx, hx, cfin);
  histcast_kernel<<<16384, 128, 0, stream>>>(hx, (float*)d_out);
  finals_kernel<<<256, 256, 0, stream>>>(hx, cfin, (float*)d_out);
}